// Round 1
// baseline (162.753 us; speedup 1.0000x reference)
//
#include <hip/hip_runtime.h>
#include <math.h>

#define N_BOIDS 8192
constexpr int   SLICES      = 16;            // lanes cooperating per boid
constexpr int   BLOCK       = 256;
constexpr int   I_PER_BLOCK = BLOCK / SLICES;  // 16 boids per block
// f32 roundings of the Python doubles 0.02**2 and 0.2**2
constexpr float SEP_R2  = 4.0000000000000008e-04f;
constexpr float PERC_R2 = 4.0000000000000001e-02f;
constexpr float EPSF    = 1e-08f;

__global__ __launch_bounds__(BLOCK) void boids_kernel(
    const float* __restrict__ pos,
    const float* __restrict__ vel,
    const float* __restrict__ noise,
    const float* __restrict__ w_sep,
    const float* __restrict__ w_ali,
    const float* __restrict__ w_coh,
    const float* __restrict__ w_noise,
    float* __restrict__ out)
{
    const int tid   = threadIdx.x;
    const int slice = tid & (SLICES - 1);
    const int i     = blockIdx.x * I_PER_BLOCK + (tid >> 4);

    const float pix = pos[2 * i];
    const float piy = pos[2 * i + 1];

    float sep_x = 0.f, sep_y = 0.f;
    float vsum_x = 0.f, vsum_y = 0.f;
    float coh_x = 0.f, coh_y = 0.f;
    float cnt = 0.f;

#pragma unroll 4
    for (int j = slice; j < N_BOIDS; j += SLICES) {
        const float2 pj = *reinterpret_cast<const float2*>(pos + 2 * j);
        const float2 vj = *reinterpret_cast<const float2*>(vel + 2 * j);

        // toroidal min-image difference, exact reference semantics
        float dx = pj.x - pix;
        dx = (dx > 0.5f)  ? dx - 1.0f : dx;
        dx = (dx < -0.5f) ? dx + 1.0f : dx;
        float dy = pj.y - piy;
        dy = (dy > 0.5f)  ? dy - 1.0f : dy;
        dy = (dy < -0.5f) ? dy + 1.0f : dy;

        // bit-exact (mul,mul,add — no FMA contraction) to match np masks
        const float d2 = __fadd_rn(__fmul_rn(dx, dx), __fmul_rn(dy, dy));
        const bool notself = (j != i);

        if (notself && (d2 <= SEP_R2)) {
            sep_x -= dx;
            sep_y -= dy;
        }
        if (notself && (d2 <= PERC_R2)) {
            cnt    += 1.0f;
            vsum_x += vj.x;
            vsum_y += vj.y;
            coh_x  += dx;
            coh_y  += dy;
        }
    }

    // butterfly reduce across the 16 cooperating lanes
#pragma unroll
    for (int m = 1; m < SLICES; m <<= 1) {
        sep_x  += __shfl_xor(sep_x, m);
        sep_y  += __shfl_xor(sep_y, m);
        vsum_x += __shfl_xor(vsum_x, m);
        vsum_y += __shfl_xor(vsum_y, m);
        coh_x  += __shfl_xor(coh_x, m);
        coh_y  += __shfl_xor(coh_y, m);
        cnt    += __shfl_xor(cnt, m);
    }

    if (slice == 0) {
        // separation: normalize
        float ns  = fmaxf(sqrtf(sep_x * sep_x + sep_y * sep_y), EPSF);
        float ssx = sep_x / ns, ssy = sep_y / ns;

        // alignment: mean neighbor velocity minus own, normalize
        float vix = vel[2 * i], viy = vel[2 * i + 1];
        float vax = vsum_x / cnt - vix;
        float vay = vsum_y / cnt - viy;
        float na  = fmaxf(sqrtf(vax * vax + vay * vay), EPSF);
        float sax = vax / na, say = vay / na;

        // cohesion: mean toroidal vector, normalize
        float pax = coh_x / cnt, pay = coh_y / cnt;
        float nc  = fmaxf(sqrtf(pax * pax + pay * pay), EPSF);
        float scx = pax / nc, scy = pay / nc;

        const float ws = w_sep[0], wa = w_ali[0], wc = w_coh[0], wn = w_noise[0];
        float ax = ws * ssx + wa * sax + wc * scx;
        float ay = ws * ssy + wa * say + wc * scy;
        // ACC_SCALE == 1.0
        ax += wn * noise[2 * i];
        ay += wn * noise[2 * i + 1];

        const float nn = sqrtf(ax * ax + ay * ay);
        if (nn > 1.0f) {
            const float s = 1.0f / fmaxf(nn, EPSF);
            ax *= s;
            ay *= s;
        }
        out[2 * i]     = ax;
        out[2 * i + 1] = ay;
    }
}

extern "C" void kernel_launch(void* const* d_in, const int* in_sizes, int n_in,
                              void* d_out, int out_size, void* d_ws, size_t ws_size,
                              hipStream_t stream) {
    const float* pos     = (const float*)d_in[0];
    const float* vel     = (const float*)d_in[1];
    const float* noise   = (const float*)d_in[2];
    const float* w_sep   = (const float*)d_in[3];
    const float* w_ali   = (const float*)d_in[4];
    const float* w_coh   = (const float*)d_in[5];
    const float* w_noise = (const float*)d_in[6];
    float* out = (float*)d_out;

    const int grid = N_BOIDS / I_PER_BLOCK;  // 512 blocks
    boids_kernel<<<grid, BLOCK, 0, stream>>>(pos, vel, noise, w_sep, w_ali,
                                             w_coh, w_noise, out);
}

// Round 2
// 43.768 us; speedup vs baseline: 3.7186x; 3.7186x over previous
//
#include <hip/hip_runtime.h>
#include <math.h>

#define N_BOIDS 8192
constexpr int   BLOCK           = 256;
constexpr int   WAVES_PER_BLOCK = BLOCK / 64;                 // 4
constexpr int   I_PER_WAVE      = 2;                          // boids per wave
constexpr int   I_PER_BLOCK     = WAVES_PER_BLOCK * I_PER_WAVE; // 8
constexpr int   TILE            = 2048;                       // j-boids per LDS tile
constexpr int   NTILES          = N_BOIDS / TILE;             // 4
// f32 roundings of the Python doubles 0.02**2 and 0.2**2
constexpr float SEP_R2  = 4.0000000000000008e-04f;
constexpr float PERC_R2 = 4.0000000000000001e-02f;
constexpr float EPSF    = 1e-08f;

__device__ __forceinline__ void finalize_boid(
    int i, const float2* __restrict__ vel, const float2* __restrict__ noise,
    float ws, float wa, float wc, float wn,
    float sx, float sy, float vx, float vy, float cx, float cy, float cntall,
    float* __restrict__ out)
{
    const float cnt = cntall - 1.0f;  // remove self (d2 == 0 passed the mask)

    // separation
    float ns  = fmaxf(sqrtf(sx * sx + sy * sy), EPSF);
    float ssx = sx / ns, ssy = sy / ns;

    // alignment: (sum_{j!=i} vj)/cnt - vi  (self was accumulated -> subtract)
    const float2 vi = vel[i];
    float vax = (vx - vi.x) / cnt - vi.x;
    float vay = (vy - vi.y) / cnt - vi.y;
    float na  = fmaxf(sqrtf(vax * vax + vay * vay), EPSF);
    float sax = vax / na, say = vay / na;

    // cohesion (self added exactly 0)
    float pax = cx / cnt, pay = cy / cnt;
    float nc  = fmaxf(sqrtf(pax * pax + pay * pay), EPSF);
    float scx = pax / nc, scy = pay / nc;

    float ax = ws * ssx + wa * sax + wc * scx;
    float ay = ws * ssy + wa * say + wc * scy;
    const float2 nz = noise[i];
    ax += wn * nz.x;
    ay += wn * nz.y;

    const float nn = sqrtf(ax * ax + ay * ay);
    if (nn > 1.0f) {
        const float s = 1.0f / fmaxf(nn, EPSF);
        ax *= s;
        ay *= s;
    }
    out[2 * i]     = ax;
    out[2 * i + 1] = ay;
}

__global__ __launch_bounds__(BLOCK, 4) void boids_kernel(
    const float2* __restrict__ pos,
    const float2* __restrict__ vel,
    const float2* __restrict__ noise,
    const float* __restrict__ w_sep,
    const float* __restrict__ w_ali,
    const float* __restrict__ w_coh,
    const float* __restrict__ w_noise,
    float* __restrict__ out)
{
    __shared__ float4 tile[TILE];  // (px, py, vx, vy) per j-boid: 32 KB

    const int tid  = threadIdx.x;
    const int lane = tid & 63;
    const int wid  = tid >> 6;
    const int w    = blockIdx.x * WAVES_PER_BLOCK + wid;
    const int i0   = w * I_PER_WAVE;
    const int i1   = i0 + 1;

    const float2 p0 = pos[i0];
    const float2 p1 = pos[i1];

    float s0x = 0.f, s0y = 0.f, v0x = 0.f, v0y = 0.f, c0x = 0.f, c0y = 0.f, n0 = 0.f;
    float s1x = 0.f, s1y = 0.f, v1x = 0.f, v1y = 0.f, c1x = 0.f, c1y = 0.f, n1 = 0.f;

    for (int t = 0; t < NTILES; ++t) {
        // stage TILE boids: pos+vel interleaved as float4
        const float4* gp = reinterpret_cast<const float4*>(pos) + t * (TILE / 2);
        const float4* gv = reinterpret_cast<const float4*>(vel) + t * (TILE / 2);
#pragma unroll
        for (int c = 0; c < TILE / 2 / BLOCK; ++c) {  // 4 iters
            const int idx  = tid + c * BLOCK;
            const float4 pp = gp[idx];   // boids 2*idx, 2*idx+1 positions
            const float4 vv = gv[idx];   // their velocities
            tile[2 * idx]     = make_float4(pp.x, pp.y, vv.x, vv.y);
            tile[2 * idx + 1] = make_float4(pp.z, pp.w, vv.z, vv.w);
        }
        __syncthreads();

#pragma unroll 4
        for (int k = 0; k < TILE / 64; ++k) {  // 32 iters
            const float4 q = tile[lane + k * 64];
            {
                float dx = q.x - p0.x; dx -= rintf(dx);   // exact toroidal wrap
                float dy = q.y - p0.y; dy -= rintf(dy);
                const float d2 = __fadd_rn(__fmul_rn(dx, dx), __fmul_rn(dy, dy));
                const float m  = (d2 <= PERC_R2) ? 1.0f : 0.0f;
                const float ms = (d2 <= SEP_R2)  ? 1.0f : 0.0f;
                n0  += m;
                v0x = fmaf(m, q.z, v0x);   v0y = fmaf(m, q.w, v0y);
                c0x = fmaf(m, dx, c0x);    c0y = fmaf(m, dy, c0y);
                s0x = fmaf(ms, -dx, s0x);  s0y = fmaf(ms, -dy, s0y);
            }
            {
                float dx = q.x - p1.x; dx -= rintf(dx);
                float dy = q.y - p1.y; dy -= rintf(dy);
                const float d2 = __fadd_rn(__fmul_rn(dx, dx), __fmul_rn(dy, dy));
                const float m  = (d2 <= PERC_R2) ? 1.0f : 0.0f;
                const float ms = (d2 <= SEP_R2)  ? 1.0f : 0.0f;
                n1  += m;
                v1x = fmaf(m, q.z, v1x);   v1y = fmaf(m, q.w, v1y);
                c1x = fmaf(m, dx, c1x);    c1y = fmaf(m, dy, c1y);
                s1x = fmaf(ms, -dx, s1x);  s1y = fmaf(ms, -dy, s1y);
            }
        }
        __syncthreads();
    }

    // full-wave butterfly reduction (all 64 lanes end with totals)
#pragma unroll
    for (int m = 1; m < 64; m <<= 1) {
        s0x += __shfl_xor(s0x, m);  s0y += __shfl_xor(s0y, m);
        v0x += __shfl_xor(v0x, m);  v0y += __shfl_xor(v0y, m);
        c0x += __shfl_xor(c0x, m);  c0y += __shfl_xor(c0y, m);
        n0  += __shfl_xor(n0,  m);
        s1x += __shfl_xor(s1x, m);  s1y += __shfl_xor(s1y, m);
        v1x += __shfl_xor(v1x, m);  v1y += __shfl_xor(v1y, m);
        c1x += __shfl_xor(c1x, m);  c1y += __shfl_xor(c1y, m);
        n1  += __shfl_xor(n1,  m);
    }

    if (lane == 0) {
        const float ws = w_sep[0], wa = w_ali[0], wc = w_coh[0], wn = w_noise[0];
        finalize_boid(i0, vel, noise, ws, wa, wc, wn,
                      s0x, s0y, v0x, v0y, c0x, c0y, n0, out);
        finalize_boid(i1, vel, noise, ws, wa, wc, wn,
                      s1x, s1y, v1x, v1y, c1x, c1y, n1, out);
    }
}

extern "C" void kernel_launch(void* const* d_in, const int* in_sizes, int n_in,
                              void* d_out, int out_size, void* d_ws, size_t ws_size,
                              hipStream_t stream) {
    const float2* pos     = (const float2*)d_in[0];
    const float2* vel     = (const float2*)d_in[1];
    const float2* noise   = (const float2*)d_in[2];
    const float*  w_sep   = (const float*)d_in[3];
    const float*  w_ali   = (const float*)d_in[4];
    const float*  w_coh   = (const float*)d_in[5];
    const float*  w_noise = (const float*)d_in[6];
    float* out = (float*)d_out;

    const int grid = N_BOIDS / I_PER_BLOCK;  // 1024 blocks
    boids_kernel<<<grid, BLOCK, 0, stream>>>(pos, vel, noise, w_sep, w_ali,
                                             w_coh, w_noise, out);
}

// Round 3
// 42.968 us; speedup vs baseline: 3.7878x; 1.0186x over previous
//
#include <hip/hip_runtime.h>
#include <math.h>

#define N_BOIDS 8192
typedef float f32x2 __attribute__((ext_vector_type(2)));
typedef float f32x4 __attribute__((ext_vector_type(4)));

constexpr int   BLOCK           = 256;
constexpr int   WAVES_PER_BLOCK = BLOCK / 64;                   // 4
constexpr int   I_PER_WAVE      = 4;                            // boids per wave
constexpr int   I_PER_BLOCK     = WAVES_PER_BLOCK * I_PER_WAVE; // 16
constexpr int   TILE            = 2048;                         // j-boids per LDS tile
constexpr int   NTILES          = N_BOIDS / TILE;               // 4
// f32 roundings of the Python doubles 0.02**2 and 0.2**2
constexpr float SEP_R2  = 4.0000000000000008e-04f;
constexpr float PERC_R2 = 4.0000000000000001e-02f;
constexpr float EPSF    = 1e-08f;

__device__ __forceinline__ void finalize_boid(
    int i, const f32x2* __restrict__ vel, const f32x2* __restrict__ noise,
    float ws, float wa, float wc, float wn,
    float sx, float sy, float vx, float vy, float cx, float cy, float cntall,
    float* __restrict__ out)
{
    const float cnt = cntall - 1.0f;  // remove self (d2 == 0 passed the mask)

    // separation
    float ns  = fmaxf(sqrtf(sx * sx + sy * sy), EPSF);
    float ssx = sx / ns, ssy = sy / ns;

    // alignment: (sum_{j!=i} vj)/cnt - vi  (self was accumulated -> subtract)
    const f32x2 vi = vel[i];
    float vax = (vx - vi.x) / cnt - vi.x;
    float vay = (vy - vi.y) / cnt - vi.y;
    float na  = fmaxf(sqrtf(vax * vax + vay * vay), EPSF);
    float sax = vax / na, say = vay / na;

    // cohesion (self added exactly 0)
    float pax = cx / cnt, pay = cy / cnt;
    float nc  = fmaxf(sqrtf(pax * pax + pay * pay), EPSF);
    float scx = pax / nc, scy = pay / nc;

    float ax = ws * ssx + wa * sax + wc * scx;
    float ay = ws * ssy + wa * say + wc * scy;
    const f32x2 nz = noise[i];
    ax += wn * nz.x;
    ay += wn * nz.y;

    const float nn = sqrtf(ax * ax + ay * ay);
    if (nn > 1.0f) {
        const float s = 1.0f / fmaxf(nn, EPSF);
        ax *= s;
        ay *= s;
    }
    out[2 * i]     = ax;
    out[2 * i + 1] = ay;
}

__global__ __launch_bounds__(BLOCK, 2) void boids_kernel(
    const f32x2* __restrict__ pos,
    const f32x2* __restrict__ vel,
    const f32x2* __restrict__ noise,
    const float* __restrict__ w_sep,
    const float* __restrict__ w_ali,
    const float* __restrict__ w_coh,
    const float* __restrict__ w_noise,
    float* __restrict__ out)
{
    __shared__ f32x4 tile[TILE];  // (px, py, vx, vy) per j-boid: 32 KB

    const int tid  = threadIdx.x;
    const int lane = tid & 63;
    const int wid  = tid >> 6;
    const int i0   = (blockIdx.x * WAVES_PER_BLOCK + wid) * I_PER_WAVE;

    f32x2 pi[I_PER_WAVE];
#pragma unroll
    for (int b = 0; b < I_PER_WAVE; ++b) pi[b] = pos[i0 + b];

    f32x2 sep[I_PER_WAVE], vs[I_PER_WAVE], coh[I_PER_WAVE];
    float cnt[I_PER_WAVE];
#pragma unroll
    for (int b = 0; b < I_PER_WAVE; ++b) {
        sep[b] = (f32x2)0.0f; vs[b] = (f32x2)0.0f; coh[b] = (f32x2)0.0f;
        cnt[b] = 0.0f;
    }

    for (int t = 0; t < NTILES; ++t) {
        // stage TILE boids: pos+vel interleaved as (px,py,vx,vy)
        const f32x4* gp = reinterpret_cast<const f32x4*>(pos) + t * (TILE / 2);
        const f32x4* gv = reinterpret_cast<const f32x4*>(vel) + t * (TILE / 2);
#pragma unroll
        for (int c = 0; c < TILE / 2 / BLOCK; ++c) {  // 4 iters
            const int idx  = tid + c * BLOCK;
            const f32x4 pp = gp[idx];   // positions of boids 2*idx, 2*idx+1
            const f32x4 vv = gv[idx];   // their velocities
            f32x4 t0; t0.x = pp.x; t0.y = pp.y; t0.z = vv.x; t0.w = vv.y;
            f32x4 t1; t1.x = pp.z; t1.y = pp.w; t1.z = vv.z; t1.w = vv.w;
            tile[2 * idx]     = t0;
            tile[2 * idx + 1] = t1;
        }
        __syncthreads();

#pragma unroll 8
        for (int k = 0; k < TILE / 64; ++k) {  // 32 iters
            const f32x4 q  = tile[lane + k * 64];
            const f32x2 qp = q.xy;
            const f32x2 qv = q.zw;
#pragma unroll
            for (int b = 0; b < I_PER_WAVE; ++b) {
                f32x2 d = qp - pi[b];                   // v_pk_add (neg)
                f32x2 r; r.x = rintf(d.x); r.y = rintf(d.y);  // exact wrap
                d = d - r;                              // v_pk_add (neg)
                const f32x2 sq = d * d;                 // v_pk_mul, per-comp RN
                const float d2 = __fadd_rn(sq.x, sq.y); // non-contractible add
                const float m  = (d2 <= PERC_R2) ? 1.0f : 0.0f;
                const float ms = (d2 <= SEP_R2)  ? 1.0f : 0.0f;
                cnt[b] += m;
                const f32x2 mm  = {m, m};
                const f32x2 mms = {ms, ms};
                vs[b]  = __builtin_elementwise_fma(mm,  qv, vs[b]);
                coh[b] = __builtin_elementwise_fma(mm,  d,  coh[b]);
                sep[b] = __builtin_elementwise_fma(mms, -d, sep[b]);
            }
        }
        __syncthreads();
    }

    // full-wave butterfly reduction (all 64 lanes end with totals)
#pragma unroll
    for (int mlev = 1; mlev < 64; mlev <<= 1) {
#pragma unroll
        for (int b = 0; b < I_PER_WAVE; ++b) {
            sep[b].x += __shfl_xor(sep[b].x, mlev);
            sep[b].y += __shfl_xor(sep[b].y, mlev);
            vs[b].x  += __shfl_xor(vs[b].x,  mlev);
            vs[b].y  += __shfl_xor(vs[b].y,  mlev);
            coh[b].x += __shfl_xor(coh[b].x, mlev);
            coh[b].y += __shfl_xor(coh[b].y, mlev);
            cnt[b]   += __shfl_xor(cnt[b],   mlev);
        }
    }

    // lanes 0..3 each finalize one boid (parallel epilogue)
    float sx = sep[0].x, sy = sep[0].y, vx = vs[0].x, vy = vs[0].y;
    float cx = coh[0].x, cy = coh[0].y, cc = cnt[0];
#pragma unroll
    for (int b = 1; b < I_PER_WAVE; ++b) {
        if (lane == b) {
            sx = sep[b].x; sy = sep[b].y; vx = vs[b].x; vy = vs[b].y;
            cx = coh[b].x; cy = coh[b].y; cc = cnt[b];
        }
    }
    if (lane < I_PER_WAVE) {
        const float ws = w_sep[0], wa = w_ali[0], wc = w_coh[0], wn = w_noise[0];
        finalize_boid(i0 + lane, vel, noise, ws, wa, wc, wn,
                      sx, sy, vx, vy, cx, cy, cc, out);
    }
}

extern "C" void kernel_launch(void* const* d_in, const int* in_sizes, int n_in,
                              void* d_out, int out_size, void* d_ws, size_t ws_size,
                              hipStream_t stream) {
    const f32x2* pos     = (const f32x2*)d_in[0];
    const f32x2* vel     = (const f32x2*)d_in[1];
    const f32x2* noise   = (const f32x2*)d_in[2];
    const float* w_sep   = (const float*)d_in[3];
    const float* w_ali   = (const float*)d_in[4];
    const float* w_coh   = (const float*)d_in[5];
    const float* w_noise = (const float*)d_in[6];
    float* out = (float*)d_out;

    const int grid = N_BOIDS / I_PER_BLOCK;  // 512 blocks
    boids_kernel<<<grid, BLOCK, 0, stream>>>(pos, vel, noise, w_sep, w_ali,
                                             w_coh, w_noise, out);
}

// Round 4
// 40.592 us; speedup vs baseline: 4.0095x; 1.0585x over previous
//
#include <hip/hip_runtime.h>
#include <math.h>

#define N_BOIDS 8192
typedef float f32x2 __attribute__((ext_vector_type(2)));
typedef float f32x4 __attribute__((ext_vector_type(4)));

constexpr int   BLOCK           = 256;
constexpr int   WAVES_PER_BLOCK = BLOCK / 64;                   // 4
constexpr int   I_PER_WAVE      = 2;                            // boids per wave
constexpr int   I_PER_BLOCK     = WAVES_PER_BLOCK * I_PER_WAVE; // 8
constexpr int   TILE            = 2048;                         // j-boids per LDS tile
constexpr int   NTILES          = N_BOIDS / TILE;               // 4
// f32 roundings of the Python doubles 0.02**2 and 0.2**2
constexpr float SEP_R2  = 4.0000000000000008e-04f;
constexpr float PERC_R2 = 4.0000000000000001e-02f;
constexpr float EPSF    = 1e-08f;

// ---- forced VOP3P packed-f32 helpers (per-component IEEE RN, same as scalar)
__device__ __forceinline__ f32x2 pk_sub(f32x2 a, f32x2 b) {
    f32x2 d;
    asm("v_pk_add_f32 %0, %1, %2 neg_lo:[0,1] neg_hi:[0,1]"
        : "=v"(d) : "v"(a), "v"(b));
    return d;
}
__device__ __forceinline__ f32x2 pk_mul(f32x2 a, f32x2 b) {
    f32x2 d;
    asm("v_pk_mul_f32 %0, %1, %2" : "=v"(d) : "v"(a), "v"(b));
    return d;
}
__device__ __forceinline__ void pk_fma_acc(f32x2& acc, f32x2 a, f32x2 b) {
    asm("v_pk_fma_f32 %0, %1, %2, %0" : "+v"(acc) : "v"(a), "v"(b));
}
// acc += (-a)*b  (neg modifier on src0 — free)
__device__ __forceinline__ void pk_fnma_acc(f32x2& acc, f32x2 a, f32x2 b) {
    asm("v_pk_fma_f32 %0, %1, %2, %0 neg_lo:[1,0,0] neg_hi:[1,0,0]"
        : "+v"(acc) : "v"(a), "v"(b));
}

__device__ __forceinline__ void finalize_boid(
    int i, const f32x2* __restrict__ vel, const f32x2* __restrict__ noise,
    float ws, float wa, float wc, float wn,
    float sx, float sy, float vx, float vy, float cx, float cy, float cntall,
    float* __restrict__ out)
{
    const float cnt = cntall - 1.0f;  // remove self (d2 == 0 passed the mask)

    // separation
    float ns  = fmaxf(sqrtf(sx * sx + sy * sy), EPSF);
    float ssx = sx / ns, ssy = sy / ns;

    // alignment: (sum_{j!=i} vj)/cnt - vi  (self accumulated -> subtract)
    const f32x2 vi = vel[i];
    float vax = (vx - vi.x) / cnt - vi.x;
    float vay = (vy - vi.y) / cnt - vi.y;
    float na  = fmaxf(sqrtf(vax * vax + vay * vay), EPSF);
    float sax = vax / na, say = vay / na;

    // cohesion (self added exactly 0)
    float pax = cx / cnt, pay = cy / cnt;
    float nc  = fmaxf(sqrtf(pax * pax + pay * pay), EPSF);
    float scx = pax / nc, scy = pay / nc;

    float ax = ws * ssx + wa * sax + wc * scx;
    float ay = ws * ssy + wa * say + wc * scy;
    const f32x2 nz = noise[i];
    ax += wn * nz.x;
    ay += wn * nz.y;

    const float nn = sqrtf(ax * ax + ay * ay);
    if (nn > 1.0f) {
        const float s = 1.0f / fmaxf(nn, EPSF);
        ax *= s;
        ay *= s;
    }
    out[2 * i]     = ax;
    out[2 * i + 1] = ay;
}

__global__ __launch_bounds__(BLOCK, 4) void boids_kernel(
    const f32x2* __restrict__ pos,
    const f32x2* __restrict__ vel,
    const f32x2* __restrict__ noise,
    const float* __restrict__ w_sep,
    const float* __restrict__ w_ali,
    const float* __restrict__ w_coh,
    const float* __restrict__ w_noise,
    float* __restrict__ out)
{
    __shared__ f32x4 tile[TILE];  // (px, py, vx, vy) per j-boid: 32 KB

    const int tid  = threadIdx.x;
    const int lane = tid & 63;
    const int wid  = tid >> 6;
    const int i0   = (blockIdx.x * WAVES_PER_BLOCK + wid) * I_PER_WAVE;

    f32x2 pi[I_PER_WAVE];
#pragma unroll
    for (int b = 0; b < I_PER_WAVE; ++b) pi[b] = pos[i0 + b];

    f32x2 sep[I_PER_WAVE], vs[I_PER_WAVE], coh[I_PER_WAVE];
    float cnt[I_PER_WAVE];
#pragma unroll
    for (int b = 0; b < I_PER_WAVE; ++b) {
        sep[b] = (f32x2)0.0f; vs[b] = (f32x2)0.0f; coh[b] = (f32x2)0.0f;
        cnt[b] = 0.0f;
    }

    for (int t = 0; t < NTILES; ++t) {
        // stage TILE boids: pos+vel interleaved as (px,py,vx,vy)
        const f32x4* gp = reinterpret_cast<const f32x4*>(pos) + t * (TILE / 2);
        const f32x4* gv = reinterpret_cast<const f32x4*>(vel) + t * (TILE / 2);
#pragma unroll
        for (int c = 0; c < TILE / 2 / BLOCK; ++c) {  // 4 iters
            const int idx  = tid + c * BLOCK;
            const f32x4 pp = gp[idx];   // positions of boids 2*idx, 2*idx+1
            const f32x4 vv = gv[idx];   // their velocities
            f32x4 t0; t0.x = pp.x; t0.y = pp.y; t0.z = vv.x; t0.w = vv.y;
            f32x4 t1; t1.x = pp.z; t1.y = pp.w; t1.z = vv.z; t1.w = vv.w;
            tile[2 * idx]     = t0;
            tile[2 * idx + 1] = t1;
        }
        __syncthreads();

#pragma unroll 8
        for (int k = 0; k < TILE / 64; ++k) {  // 32 iters
            const f32x4 q  = tile[lane + k * 64];
            const f32x2 qp = q.xy;
            const f32x2 qv = q.zw;
#pragma unroll
            for (int b = 0; b < I_PER_WAVE; ++b) {
                f32x2 d = pk_sub(qp, pi[b]);            // v_pk_add neg
                f32x2 r; r.x = rintf(d.x); r.y = rintf(d.y);  // exact wrap
                d = pk_sub(d, r);
                const f32x2 sq = pk_mul(d, d);          // per-comp RN
                const float d2 = __fadd_rn(sq.x, sq.y); // non-contractible
                const bool inp = (d2 <= PERC_R2);
                const bool ins = (d2 <= SEP_R2);
                f32x2 mm;  mm.x  = inp ? 1.0f : 0.0f;  mm.y  = mm.x;
                f32x2 mms; mms.x = ins ? 1.0f : 0.0f;  mms.y = mms.x;
                cnt[b] += mm.x;
                pk_fma_acc(vs[b],  mm,  qv);
                pk_fma_acc(coh[b], mm,  d);
                pk_fnma_acc(sep[b], mms, d);
            }
        }
        __syncthreads();
    }

    // full-wave butterfly reduction (all 64 lanes end with totals)
#pragma unroll
    for (int mlev = 1; mlev < 64; mlev <<= 1) {
#pragma unroll
        for (int b = 0; b < I_PER_WAVE; ++b) {
            sep[b].x += __shfl_xor(sep[b].x, mlev);
            sep[b].y += __shfl_xor(sep[b].y, mlev);
            vs[b].x  += __shfl_xor(vs[b].x,  mlev);
            vs[b].y  += __shfl_xor(vs[b].y,  mlev);
            coh[b].x += __shfl_xor(coh[b].x, mlev);
            coh[b].y += __shfl_xor(coh[b].y, mlev);
            cnt[b]   += __shfl_xor(cnt[b],   mlev);
        }
    }

    // lanes 0..1 each finalize one boid (parallel epilogue)
    float sx = sep[0].x, sy = sep[0].y, vx = vs[0].x, vy = vs[0].y;
    float cx = coh[0].x, cy = coh[0].y, cc = cnt[0];
#pragma unroll
    for (int b = 1; b < I_PER_WAVE; ++b) {
        if (lane == b) {
            sx = sep[b].x; sy = sep[b].y; vx = vs[b].x; vy = vs[b].y;
            cx = coh[b].x; cy = coh[b].y; cc = cnt[b];
        }
    }
    if (lane < I_PER_WAVE) {
        const float ws = w_sep[0], wa = w_ali[0], wc = w_coh[0], wn = w_noise[0];
        finalize_boid(i0 + lane, vel, noise, ws, wa, wc, wn,
                      sx, sy, vx, vy, cx, cy, cc, out);
    }
}

extern "C" void kernel_launch(void* const* d_in, const int* in_sizes, int n_in,
                              void* d_out, int out_size, void* d_ws, size_t ws_size,
                              hipStream_t stream) {
    const f32x2* pos     = (const f32x2*)d_in[0];
    const f32x2* vel     = (const f32x2*)d_in[1];
    const f32x2* noise   = (const f32x2*)d_in[2];
    const float* w_sep   = (const float*)d_in[3];
    const float* w_ali   = (const float*)d_in[4];
    const float* w_coh   = (const float*)d_in[5];
    const float* w_noise = (const float*)d_in[6];
    float* out = (float*)d_out;

    const int grid = N_BOIDS / I_PER_BLOCK;  // 1024 blocks
    boids_kernel<<<grid, BLOCK, 0, stream>>>(pos, vel, noise, w_sep, w_ali,
                                             w_coh, w_noise, out);
}

// Round 5
// 34.362 us; speedup vs baseline: 4.7364x; 1.1813x over previous
//
#include <hip/hip_runtime.h>
#include <math.h>

#define N_BOIDS 8192
typedef float f32x2 __attribute__((ext_vector_type(2)));
typedef float f32x4 __attribute__((ext_vector_type(4)));

constexpr int   BLOCK           = 256;
constexpr int   WAVES_PER_BLOCK = BLOCK / 64;                   // 4
constexpr int   I_PER_WAVE      = 2;                            // boids per wave
constexpr int   I_PER_BLOCK     = WAVES_PER_BLOCK * I_PER_WAVE; // 8
constexpr int   TILE            = 2048;                         // j-boids per LDS tile
constexpr int   NTILES          = N_BOIDS / TILE;               // 4
// f32 roundings of the Python doubles 0.02**2 and 0.2**2
constexpr float SEP_R2  = 4.0000000000000008e-04f;
constexpr float PERC_R2 = 4.0000000000000001e-02f;
constexpr float EPSF    = 1e-08f;

__device__ __forceinline__ void finalize_boid(
    int i, const f32x2* __restrict__ vel, const f32x2* __restrict__ noise,
    float ws, float wa, float wc, float wn,
    float sx, float sy, float vx, float vy, float cx, float cy, float cntall,
    float* __restrict__ out)
{
    const float cnt = cntall - 1.0f;  // remove self (d2 == 0 passed the mask)

    // separation
    float ns  = fmaxf(sqrtf(sx * sx + sy * sy), EPSF);
    float ssx = sx / ns, ssy = sy / ns;

    // alignment: (sum incl. self - vi)/cnt - vi
    const f32x2 vi = vel[i];
    float vax = (vx - vi.x) / cnt - vi.x;
    float vay = (vy - vi.y) / cnt - vi.y;
    float na  = fmaxf(sqrtf(vax * vax + vay * vay), EPSF);
    float sax = vax / na, say = vay / na;

    // cohesion (self added exactly 0)
    float pax = cx / cnt, pay = cy / cnt;
    float nc  = fmaxf(sqrtf(pax * pax + pay * pay), EPSF);
    float scx = pax / nc, scy = pay / nc;

    float ax = ws * ssx + wa * sax + wc * scx;
    float ay = ws * ssy + wa * say + wc * scy;
    const f32x2 nz = noise[i];
    ax += wn * nz.x;
    ay += wn * nz.y;

    const float nn = sqrtf(ax * ax + ay * ay);
    if (nn > 1.0f) {
        const float s = 1.0f / fmaxf(nn, EPSF);
        ax *= s;
        ay *= s;
    }
    out[2 * i]     = ax;
    out[2 * i + 1] = ay;
}

__global__ __launch_bounds__(BLOCK, 4) void boids_kernel(
    const f32x2* __restrict__ pos,
    const f32x2* __restrict__ vel,
    const f32x2* __restrict__ noise,
    const float* __restrict__ w_sep,
    const float* __restrict__ w_ali,
    const float* __restrict__ w_coh,
    const float* __restrict__ w_noise,
    float* __restrict__ out)
{
    __shared__ f32x4 tile[TILE];  // (px, py, vx, vy) per j-boid: 32 KB

    const int tid  = threadIdx.x;
    const int lane = tid & 63;
    const int wid  = tid >> 6;
    const int i0   = (blockIdx.x * WAVES_PER_BLOCK + wid) * I_PER_WAVE;

    const f32x2 P0 = pos[i0];
    const f32x2 P1 = pos[i0 + 1];
    const float vperc = PERC_R2;
    const float vsep  = SEP_R2;

    float n0 = 0.f, s0x = 0.f, s0y = 0.f, v0x = 0.f, v0y = 0.f, c0x = 0.f, c0y = 0.f;
    float n1 = 0.f, s1x = 0.f, s1y = 0.f, v1x = 0.f, v1y = 0.f, c1x = 0.f, c1y = 0.f;

    for (int t = 0; t < NTILES; ++t) {
        // stage TILE boids: pos+vel interleaved as (px,py,vx,vy)
        const f32x4* gp = reinterpret_cast<const f32x4*>(pos) + t * (TILE / 2);
        const f32x4* gv = reinterpret_cast<const f32x4*>(vel) + t * (TILE / 2);
#pragma unroll
        for (int c = 0; c < TILE / 2 / BLOCK; ++c) {  // 4 iters
            const int idx  = tid + c * BLOCK;
            const f32x4 pp = gp[idx];   // positions of boids 2*idx, 2*idx+1
            const f32x4 vv = gv[idx];   // their velocities
            f32x4 t0; t0.x = pp.x; t0.y = pp.y; t0.z = vv.x; t0.w = vv.y;
            f32x4 t1; t1.x = pp.z; t1.y = pp.w; t1.z = vv.z; t1.w = vv.w;
            tile[2 * idx]     = t0;
            tile[2 * idx + 1] = t1;
        }
        __syncthreads();

#pragma unroll 8
        for (int k = 0; k < TILE / 64; ++k) {  // 32 iters
            const f32x4 q = tile[lane + k * 64];
            float dx, dy, ta, tb, m;
            // Exactly 40 VALU instrs for the 2 boids; masks via vcc,
            // inline 0/1.0 consts, neg-modifier fma for separation.
            asm(
                // ---- boid 0
                "v_sub_f32   %[dx], %[qx], %[p0x]\n\t"
                "v_sub_f32   %[dy], %[qy], %[p0y]\n\t"
                "v_rndne_f32 %[ta], %[dx]\n\t"
                "v_rndne_f32 %[tb], %[dy]\n\t"
                "v_sub_f32   %[dx], %[dx], %[ta]\n\t"
                "v_sub_f32   %[dy], %[dy], %[tb]\n\t"
                "v_mul_f32   %[ta], %[dx], %[dx]\n\t"
                "v_mul_f32   %[tb], %[dy], %[dy]\n\t"
                "v_add_f32   %[ta], %[ta], %[tb]\n\t"
                "v_cmp_ge_f32 vcc, %[vperc], %[ta]\n\t"
                "v_cndmask_b32 %[m], 0, 1.0, vcc\n\t"
                "v_add_f32   %[n0], %[n0], %[m]\n\t"
                "v_fmac_f32  %[v0x], %[m], %[qz]\n\t"
                "v_fmac_f32  %[v0y], %[m], %[qw]\n\t"
                "v_fmac_f32  %[c0x], %[m], %[dx]\n\t"
                "v_fmac_f32  %[c0y], %[m], %[dy]\n\t"
                "v_cmp_ge_f32 vcc, %[vsep], %[ta]\n\t"
                "v_cndmask_b32 %[m], 0, 1.0, vcc\n\t"
                "v_fma_f32   %[s0x], -%[m], %[dx], %[s0x]\n\t"
                "v_fma_f32   %[s0y], -%[m], %[dy], %[s0y]\n\t"
                // ---- boid 1
                "v_sub_f32   %[dx], %[qx], %[p1x]\n\t"
                "v_sub_f32   %[dy], %[qy], %[p1y]\n\t"
                "v_rndne_f32 %[ta], %[dx]\n\t"
                "v_rndne_f32 %[tb], %[dy]\n\t"
                "v_sub_f32   %[dx], %[dx], %[ta]\n\t"
                "v_sub_f32   %[dy], %[dy], %[tb]\n\t"
                "v_mul_f32   %[ta], %[dx], %[dx]\n\t"
                "v_mul_f32   %[tb], %[dy], %[dy]\n\t"
                "v_add_f32   %[ta], %[ta], %[tb]\n\t"
                "v_cmp_ge_f32 vcc, %[vperc], %[ta]\n\t"
                "v_cndmask_b32 %[m], 0, 1.0, vcc\n\t"
                "v_add_f32   %[n1], %[n1], %[m]\n\t"
                "v_fmac_f32  %[v1x], %[m], %[qz]\n\t"
                "v_fmac_f32  %[v1y], %[m], %[qw]\n\t"
                "v_fmac_f32  %[c1x], %[m], %[dx]\n\t"
                "v_fmac_f32  %[c1y], %[m], %[dy]\n\t"
                "v_cmp_ge_f32 vcc, %[vsep], %[ta]\n\t"
                "v_cndmask_b32 %[m], 0, 1.0, vcc\n\t"
                "v_fma_f32   %[s1x], -%[m], %[dx], %[s1x]\n\t"
                "v_fma_f32   %[s1y], -%[m], %[dy], %[s1y]\n\t"
                : [dx] "=&v"(dx), [dy] "=&v"(dy), [ta] "=&v"(ta),
                  [tb] "=&v"(tb), [m] "=&v"(m),
                  [n0] "+v"(n0), [s0x] "+v"(s0x), [s0y] "+v"(s0y),
                  [v0x] "+v"(v0x), [v0y] "+v"(v0y), [c0x] "+v"(c0x), [c0y] "+v"(c0y),
                  [n1] "+v"(n1), [s1x] "+v"(s1x), [s1y] "+v"(s1y),
                  [v1x] "+v"(v1x), [v1y] "+v"(v1y), [c1x] "+v"(c1x), [c1y] "+v"(c1y)
                : [qx] "v"(q.x), [qy] "v"(q.y), [qz] "v"(q.z), [qw] "v"(q.w),
                  [p0x] "v"(P0.x), [p0y] "v"(P0.y),
                  [p1x] "v"(P1.x), [p1y] "v"(P1.y),
                  [vperc] "v"(vperc), [vsep] "v"(vsep)
                : "vcc");
        }
        __syncthreads();
    }

    // full-wave butterfly reduction (all 64 lanes end with totals)
#pragma unroll
    for (int mlev = 1; mlev < 64; mlev <<= 1) {
        n0  += __shfl_xor(n0,  mlev);
        s0x += __shfl_xor(s0x, mlev);  s0y += __shfl_xor(s0y, mlev);
        v0x += __shfl_xor(v0x, mlev);  v0y += __shfl_xor(v0y, mlev);
        c0x += __shfl_xor(c0x, mlev);  c0y += __shfl_xor(c0y, mlev);
        n1  += __shfl_xor(n1,  mlev);
        s1x += __shfl_xor(s1x, mlev);  s1y += __shfl_xor(s1y, mlev);
        v1x += __shfl_xor(v1x, mlev);  v1y += __shfl_xor(v1y, mlev);
        c1x += __shfl_xor(c1x, mlev);  c1y += __shfl_xor(c1y, mlev);
    }

    // lanes 0..1 each finalize one boid (parallel epilogue)
    float sx = s0x, sy = s0y, vx = v0x, vy = v0y, cx = c0x, cy = c0y, cc = n0;
    if (lane == 1) {
        sx = s1x; sy = s1y; vx = v1x; vy = v1y; cx = c1x; cy = c1y; cc = n1;
    }
    if (lane < I_PER_WAVE) {
        const float ws = w_sep[0], wa = w_ali[0], wc = w_coh[0], wn = w_noise[0];
        finalize_boid(i0 + lane, vel, noise, ws, wa, wc, wn,
                      sx, sy, vx, vy, cx, cy, cc, out);
    }
}

extern "C" void kernel_launch(void* const* d_in, const int* in_sizes, int n_in,
                              void* d_out, int out_size, void* d_ws, size_t ws_size,
                              hipStream_t stream) {
    const f32x2* pos     = (const f32x2*)d_in[0];
    const f32x2* vel     = (const f32x2*)d_in[1];
    const f32x2* noise   = (const f32x2*)d_in[2];
    const float* w_sep   = (const float*)d_in[3];
    const float* w_ali   = (const float*)d_in[4];
    const float* w_coh   = (const float*)d_in[5];
    const float* w_noise = (const float*)d_in[6];
    float* out = (float*)d_out;

    const int grid = N_BOIDS / I_PER_BLOCK;  // 1024 blocks
    boids_kernel<<<grid, BLOCK, 0, stream>>>(pos, vel, noise, w_sep, w_ali,
                                             w_coh, w_noise, out);
}